// Round 3
// baseline (148499.011 us; speedup 1.0000x reference)
//
#include <hip/hip_runtime.h>
#include <cstdint>
#include <cstddef>

#define LSTM_D  512
#define LSTM_4D 2048
#define LSTM_L  32768
#define REC_G   32      // workgroups in recurrent kernel (each owns 16 d's)
#define REC_DPW 16      // d-indices per workgroup

// Workspace layout:
//   ws +     0 : ctr   (4 B)     step-completion counter
//   ws +   256 : hbuf  (2*512 f)  double-buffered h
//   ws +  4608 : cbuf  (512 f)    c carry between chunk launches
//   ws + 65536 : xbuf  (C*2048 f) x-projection for current chunk
#define WS_XBUF_OFF 65536

// ---------------------------------------------------------------------------
// GEMM: xbuf[C][2048] = xs_chunk[C][512] @ Wi[512][2048] + b
// 64x64 tile, 256 threads, 4x4 micro-tile, BK=16, fp32 vector ALU.
// ---------------------------------------------------------------------------
__global__ __launch_bounds__(256)
void gemm_xproj(const float* __restrict__ A,
                const float* __restrict__ B,
                const float* __restrict__ bias,
                float* __restrict__ C)
{
    __shared__ float As[16][64];   // [k][row]
    __shared__ float Bs[16][64];   // [k][col]
    const int tid  = threadIdx.x;
    const int row0 = blockIdx.y * 64;
    const int col0 = blockIdx.x * 64;
    const int tx   = tid & 15;          // micro-tile col group
    const int ty   = tid >> 4;          // micro-tile row group
    const int lr   = tid >> 2;          // A-loader row 0..63
    const int lk4  = (tid & 3) * 4;     // A-loader k quad
    const int bk   = tid >> 4;          // B-loader k 0..15
    const int bc4  = (tid & 15) * 4;    // B-loader col quad

    float acc[4][4] = {};

    for (int k0 = 0; k0 < LSTM_D; k0 += 16) {
        float4 av = *(const float4*)(A + (size_t)(row0 + lr) * LSTM_D + k0 + lk4);
        float4 bv = *(const float4*)(B + (size_t)(k0 + bk) * LSTM_4D + col0 + bc4);
        __syncthreads();   // protect previous iteration's LDS reads
        As[lk4 + 0][lr] = av.x;
        As[lk4 + 1][lr] = av.y;
        As[lk4 + 2][lr] = av.z;
        As[lk4 + 3][lr] = av.w;
        *(float4*)(&Bs[bk][bc4]) = bv;
        __syncthreads();
#pragma unroll
        for (int k = 0; k < 16; ++k) {
            float4 a4 = *(const float4*)(&As[k][ty * 4]);
            float4 b4 = *(const float4*)(&Bs[k][tx * 4]);
            acc[0][0] = fmaf(a4.x, b4.x, acc[0][0]);
            acc[0][1] = fmaf(a4.x, b4.y, acc[0][1]);
            acc[0][2] = fmaf(a4.x, b4.z, acc[0][2]);
            acc[0][3] = fmaf(a4.x, b4.w, acc[0][3]);
            acc[1][0] = fmaf(a4.y, b4.x, acc[1][0]);
            acc[1][1] = fmaf(a4.y, b4.y, acc[1][1]);
            acc[1][2] = fmaf(a4.y, b4.z, acc[1][2]);
            acc[1][3] = fmaf(a4.y, b4.w, acc[1][3]);
            acc[2][0] = fmaf(a4.z, b4.x, acc[2][0]);
            acc[2][1] = fmaf(a4.z, b4.y, acc[2][1]);
            acc[2][2] = fmaf(a4.z, b4.z, acc[2][2]);
            acc[2][3] = fmaf(a4.z, b4.w, acc[2][3]);
            acc[3][0] = fmaf(a4.w, b4.x, acc[3][0]);
            acc[3][1] = fmaf(a4.w, b4.y, acc[3][1]);
            acc[3][2] = fmaf(a4.w, b4.z, acc[3][2]);
            acc[3][3] = fmaf(a4.w, b4.w, acc[3][3]);
        }
    }

    float4 bb = *(const float4*)(bias + col0 + tx * 4);
#pragma unroll
    for (int i = 0; i < 4; ++i) {
        float4 o;
        o.x = acc[i][0] + bb.x;
        o.y = acc[i][1] + bb.y;
        o.z = acc[i][2] + bb.z;
        o.w = acc[i][3] + bb.w;
        *(float4*)(C + (size_t)(row0 + ty * 4 + i) * LSTM_4D + col0 + tx * 4) = o;
    }
}

// ---------------------------------------------------------------------------
// Persistent recurrent kernel for one chunk of `steps` steps starting at
// global step t0. 32 wgs x 256 threads, all co-resident (grid=32 << 256 CUs).
//
// wg g owns d in [g*16, g*16+16). Its 64 Wh columns {gate*512+d} live in
// VGPRs: thread (wave w, lane l): part = (l>>2) in [0,16) -> k-range
// [part*32, part*32+32); d_in = l&3 -> d_local = w*4+d_in. All 16 k-parts of
// a given d sit in ONE wave -> shfl_xor reduction, no LDS.
//
// Sync: global counter ctr (agent scope, persists across chunk launches
// within one kernel_launch call). After writing its h-slice for step t,
// each wg adds 1 (release). A wg enters step t only when ctr >= 32*t.
// h is double-buffered by t&1: overwriting buffer (t&1) at step t+2 needs
// ctr >= 32*(t+2), i.e. every wg finished step t+1, whose reads of buffer
// (t&1) precede its increment -> no overwrite-while-reading race.
// Bounded spin: converts any deadlock into fast-wrong-finish (diagnosable).
// ---------------------------------------------------------------------------
__global__ __launch_bounds__(256, 1)
void lstm_rec(const float* __restrict__ xp,    // chunk's [steps][2048]
              const float* __restrict__ Wh,
              const float* __restrict__ h0,
              const float* __restrict__ c0,
              float* __restrict__ out,
              unsigned int* __restrict__ ctr,
              float* __restrict__ hbuf,        // 2 * 512 floats
              float* __restrict__ cbuf,        // 512 floats
              int t0, int steps)
{
    const int g      = blockIdx.x;
    const int tid    = threadIdx.x;
    const int wave   = tid >> 6;
    const int lane   = tid & 63;
    const int part   = lane >> 2;               // 0..15 (k-part)
    const int d_in   = lane & 3;
    const int d_glob = g * REC_DPW + wave * 4 + d_in;
    const int k0     = part * 32;
    const bool head  = (part == 0);             // lanes 0..3 per wave do gates

    // Load this thread's Wh fragment into registers: wreg[gate][k_local].
    float wreg[4][32];
#pragma unroll
    for (int gate = 0; gate < 4; ++gate) {
        const float* wcol = Wh + (size_t)k0 * LSTM_4D + gate * LSTM_D + d_glob;
#pragma unroll
        for (int k = 0; k < 32; ++k)
            wreg[gate][k] = wcol[(size_t)k * LSTM_4D];
    }

    float c_val = 0.f;
    if (head) c_val = (t0 == 0) ? c0[d_glob] : cbuf[d_glob];

    bool dead = false;   // set if the spin barrier ever times out

    for (int ts = 0; ts < steps; ++ts) {
        const int t = t0 + ts;

        // Prefetch x_proj row for this step BEFORE spinning (independent of h).
        float xpi = 0.f, xpf = 0.f, xpg = 0.f, xpo = 0.f;
        if (head) {
            const float* row = xp + (size_t)ts * LSTM_4D + d_glob;
            xpi = row[0];
            xpf = row[LSTM_D];
            xpg = row[2 * LSTM_D];
            xpo = row[3 * LSTM_D];
        }

        if (t > 0) {
            if (tid == 0 && !dead) {
                const unsigned target = (unsigned)REC_G * (unsigned)t;
                int spins = 0;
                while (__hip_atomic_load(ctr, __ATOMIC_ACQUIRE,
                                         __HIP_MEMORY_SCOPE_AGENT) < target) {
                    if (++spins > 10000000) { dead = true; break; }
                }
            }
            __syncthreads();
        }

        const float* hsrc = (t == 0) ? (h0 + k0)
                                     : (hbuf + ((t - 1) & 1) * LSTM_D + k0);
        float hreg[32];
#pragma unroll
        for (int k = 0; k < 32; ++k)
            hreg[k] = __hip_atomic_load((float*)(hsrc + k), __ATOMIC_RELAXED,
                                        __HIP_MEMORY_SCOPE_AGENT);

        float a0 = 0.f, a1 = 0.f, a2 = 0.f, a3 = 0.f;
#pragma unroll
        for (int k = 0; k < 32; ++k) {
            a0 = fmaf(hreg[k], wreg[0][k], a0);
            a1 = fmaf(hreg[k], wreg[1][k], a1);
            a2 = fmaf(hreg[k], wreg[2][k], a2);
            a3 = fmaf(hreg[k], wreg[3][k], a3);
        }

        // Reduce across the 16 k-parts (lane bits 2..5) within the wave.
#pragma unroll
        for (int m = 4; m <= 32; m <<= 1) {
            a0 += __shfl_xor(a0, m, 64);
            a1 += __shfl_xor(a1, m, 64);
            a2 += __shfl_xor(a2, m, 64);
            a3 += __shfl_xor(a3, m, 64);
        }

        if (head) {
            float yi = xpi + a0;
            float yf = xpf + a1;
            float yg = xpg + a2;
            float yo = xpo + a3;
            float si = 1.f / (1.f + __expf(-yi));
            float sf = 1.f / (1.f + __expf(-yf));
            float so = 1.f / (1.f + __expf(-yo));
            float tg = tanhf(yg);
            c_val = fmaf(sf, c_val, si * tg);
            float h = so * tanhf(c_val);
            out[(size_t)t * LSTM_D + d_glob] = h;
            __hip_atomic_store(hbuf + (t & 1) * LSTM_D + d_glob, h,
                               __ATOMIC_RELAXED, __HIP_MEMORY_SCOPE_AGENT);
        }

        // __syncthreads drains vmcnt(0): h stores have reached the coherence
        // point before tid 0 publishes the release increment.
        __syncthreads();
        if (tid == 0)
            __hip_atomic_fetch_add(ctr, 1u, __ATOMIC_RELEASE,
                                   __HIP_MEMORY_SCOPE_AGENT);
    }

    // Persist c carry for the next chunk launch (kernel boundary flushes it).
    if (head) cbuf[d_glob] = c_val;
}

// ---------------------------------------------------------------------------
extern "C" void kernel_launch(void* const* d_in, const int* in_sizes, int n_in,
                              void* d_out, int out_size, void* d_ws, size_t ws_size,
                              hipStream_t stream)
{
    const float* xs = (const float*)d_in[0];   // [L, 512]
    const float* Wi = (const float*)d_in[1];   // [512, 2048]
    const float* Wh = (const float*)d_in[2];   // [512, 2048]
    const float* b  = (const float*)d_in[3];   // [2048]
    const float* c0 = (const float*)d_in[4];   // [512]
    const float* h0 = (const float*)d_in[5];   // [512]
    float* out = (float*)d_out;                // [L, 512]

    uint8_t* ws = (uint8_t*)d_ws;
    unsigned int* ctr = (unsigned int*)ws;
    float* hbuf       = (float*)(ws + 256);
    float* cbuf       = (float*)(ws + 4608);
    float* xbuf       = (float*)(ws + WS_XBUF_OFF);

    // Largest power-of-two chunk whose xbuf fits in the workspace.
    int C = LSTM_L;
    while (C > 64 &&
           (size_t)WS_XBUF_OFF + (size_t)C * LSTM_4D * sizeof(float) > ws_size)
        C >>= 1;

    // Zero ctr/hbuf/cbuf (ws is poisoned 0xAA before every call).
    (void)hipMemsetAsync(ws, 0, 8192, stream);

    const int nChunks = LSTM_L / C;
    for (int k = 0; k < nChunks; ++k) {
        dim3 ggrid(LSTM_4D / 64, C / 64);
        gemm_xproj<<<ggrid, 256, 0, stream>>>(xs + (size_t)k * C * LSTM_D,
                                              Wi, b, xbuf);
        lstm_rec<<<REC_G, 256, 0, stream>>>(xbuf, Wh, h0, c0, out,
                                            ctr, hbuf, cbuf, k * C, C);
    }
}

// Round 4
// 140385.999 us; speedup vs baseline: 1.0578x; 1.0578x over previous
//
#include <hip/hip_runtime.h>
#include <cstdint>
#include <cstddef>

#define LSTM_D  512
#define LSTM_4D 2048
#define LSTM_L  32768
#define REC_G   32      // workgroups in recurrent kernel
#define REC_DPW 16      // d-indices per workgroup
#define REC_THR (REC_G * 256)   // 8192 recurrent threads

// Workspace layout:
//   ws +     0 : flags[32] (u32)  per-wg step-completion flags
//   ws +   256 : hbuf (2*512 f)   double-buffered h
//   ws +  4608 : cbuf (512 f)     c carry between chunk launches
//   ws + 65536 : wpack (8192*32 float4 = 4 MB) packed Wh
//   ws + 65536 + 4 MB : xbuf (C*2048 f) x-projection chunk
#define WS_WPACK_OFF 65536
#define WS_XBUF_OFF  (65536 + (size_t)REC_THR * 32 * sizeof(float4))

// ---------------------------------------------------------------------------
// GEMM: xbuf[C][2048] = xs_chunk[C][512] @ Wi[512][2048] + b
// ---------------------------------------------------------------------------
__global__ __launch_bounds__(256)
void gemm_xproj(const float* __restrict__ A,
                const float* __restrict__ B,
                const float* __restrict__ bias,
                float* __restrict__ C)
{
    __shared__ float As[16][64];   // [k][row]
    __shared__ float Bs[16][64];   // [k][col]
    const int tid  = threadIdx.x;
    const int row0 = blockIdx.y * 64;
    const int col0 = blockIdx.x * 64;
    const int tx   = tid & 15;
    const int ty   = tid >> 4;
    const int lr   = tid >> 2;
    const int lk4  = (tid & 3) * 4;
    const int bk   = tid >> 4;
    const int bc4  = (tid & 15) * 4;

    float acc[4][4] = {};

    for (int k0 = 0; k0 < LSTM_D; k0 += 16) {
        float4 av = *(const float4*)(A + (size_t)(row0 + lr) * LSTM_D + k0 + lk4);
        float4 bv = *(const float4*)(B + (size_t)(k0 + bk) * LSTM_4D + col0 + bc4);
        __syncthreads();
        As[lk4 + 0][lr] = av.x;
        As[lk4 + 1][lr] = av.y;
        As[lk4 + 2][lr] = av.z;
        As[lk4 + 3][lr] = av.w;
        *(float4*)(&Bs[bk][bc4]) = bv;
        __syncthreads();
#pragma unroll
        for (int k = 0; k < 16; ++k) {
            float4 a4 = *(const float4*)(&As[k][ty * 4]);
            float4 b4 = *(const float4*)(&Bs[k][tx * 4]);
            acc[0][0] = fmaf(a4.x, b4.x, acc[0][0]);
            acc[0][1] = fmaf(a4.x, b4.y, acc[0][1]);
            acc[0][2] = fmaf(a4.x, b4.z, acc[0][2]);
            acc[0][3] = fmaf(a4.x, b4.w, acc[0][3]);
            acc[1][0] = fmaf(a4.y, b4.x, acc[1][0]);
            acc[1][1] = fmaf(a4.y, b4.y, acc[1][1]);
            acc[1][2] = fmaf(a4.y, b4.z, acc[1][2]);
            acc[1][3] = fmaf(a4.y, b4.w, acc[1][3]);
            acc[2][0] = fmaf(a4.z, b4.x, acc[2][0]);
            acc[2][1] = fmaf(a4.z, b4.y, acc[2][1]);
            acc[2][2] = fmaf(a4.z, b4.z, acc[2][2]);
            acc[2][3] = fmaf(a4.z, b4.w, acc[2][3]);
            acc[3][0] = fmaf(a4.w, b4.x, acc[3][0]);
            acc[3][1] = fmaf(a4.w, b4.y, acc[3][1]);
            acc[3][2] = fmaf(a4.w, b4.z, acc[3][2]);
            acc[3][3] = fmaf(a4.w, b4.w, acc[3][3]);
        }
    }

    float4 bb = *(const float4*)(bias + col0 + tx * 4);
#pragma unroll
    for (int i = 0; i < 4; ++i) {
        float4 o;
        o.x = acc[i][0] + bb.x;
        o.y = acc[i][1] + bb.y;
        o.z = acc[i][2] + bb.z;
        o.w = acc[i][3] + bb.w;
        *(float4*)(C + (size_t)(row0 + ty * 4 + i) * LSTM_4D + col0 + tx * 4) = o;
    }
}

// ---------------------------------------------------------------------------
// Pack Wh into per-thread register-load order.
// Thread thr (of 8192): g=thr>>8, tid=thr&255, wave=tid>>6, lane=tid&63,
// p=lane>>2 (k-part), d_in=lane&3, d=g*16+wave*4+d_in, k-range [p*32,p*32+32).
// Slot i = j*4+e (j=0..7 unroll step, e=0..3 h4 component) holds the 4 gate
// weights for k = p*32 + ((j+p)&7)*4 + e.  The (j+p)&7 rotation makes the
// LDS h reads bank-conflict-free while keeping kernel-side w[] indices static.
// Layout wp[i*8192 + thr] -> lane-coalesced dwordx4 loads in lstm_rec.
// ---------------------------------------------------------------------------
__global__ __launch_bounds__(256)
void pack_wh(const float* __restrict__ Wh, float4* __restrict__ wp)
{
    const int thr  = blockIdx.x * 256 + threadIdx.x;
    const int g    = thr >> 8;
    const int tid  = thr & 255;
    const int wave = tid >> 6;
    const int lane = tid & 63;
    const int p    = lane >> 2;
    const int d_in = lane & 3;
    const int d    = g * REC_DPW + wave * 4 + d_in;

    for (int j = 0; j < 8; ++j) {
        const int c = (j + p) & 7;
        for (int e = 0; e < 4; ++e) {
            const int k = p * 32 + c * 4 + e;
            float4 w;
            w.x = Wh[(size_t)k * LSTM_4D + 0 * LSTM_D + d];
            w.y = Wh[(size_t)k * LSTM_4D + 1 * LSTM_D + d];
            w.z = Wh[(size_t)k * LSTM_4D + 2 * LSTM_D + d];
            w.w = Wh[(size_t)k * LSTM_4D + 3 * LSTM_D + d];
            wp[(size_t)(j * 4 + e) * REC_THR + thr] = w;
        }
    }
}

// ---------------------------------------------------------------------------
// Persistent recurrent kernel, one chunk of `steps` steps from t0.
// Sync: flags[g] = steps completed by wg g (release store, no RMW).
// Wave 0 polls all 32 flags with one coalesced load + ballot.
// h double-buffered in global (t&1); staged through LDS each step.
// Correctness of buffer reuse: entering step t+2 requires all flags >= t+2,
// i.e. every wg finished step t+1, whose h reads of buffer (t&1) precede its
// flag publication -> no overwrite-while-reading race.
// ---------------------------------------------------------------------------
__global__ __launch_bounds__(256, 1)
void lstm_rec(const float4* __restrict__ wp,
              const float* __restrict__ xp,    // chunk's [steps][2048]
              const float* __restrict__ h0,
              const float* __restrict__ c0,
              float* __restrict__ out,
              unsigned int* __restrict__ flags,
              float* __restrict__ hbuf,        // 2 * 512 floats
              float* __restrict__ cbuf,        // 512 floats
              int t0, int steps)
{
    __shared__ float hs[LSTM_D];

    const int g      = blockIdx.x;
    const int tid    = threadIdx.x;
    const int wave   = tid >> 6;
    const int lane   = tid & 63;
    const int p      = lane >> 2;               // k-part 0..15
    const int d_in   = lane & 3;
    const int d_glob = g * REC_DPW + wave * 4 + d_in;
    const bool head  = (p == 0);
    const int  thr   = g * 256 + tid;

    // Weights: 32 float4 = 128 VGPRs, all indices compile-time constant.
    float4 w[32];
#pragma unroll
    for (int i = 0; i < 32; ++i)
        w[i] = wp[(size_t)i * REC_THR + thr];

    float c_val = 0.f;
    if (head) c_val = (t0 == 0) ? c0[d_glob] : cbuf[d_glob];

    for (int ts = 0; ts < steps; ++ts) {
        const int t = t0 + ts;

        // Prefetch x_proj row (independent of h) before any waiting.
        float xpi = 0.f, xpf = 0.f, xpg = 0.f, xpo = 0.f;
        if (head) {
            const float* row = xp + (size_t)ts * LSTM_4D + d_glob;
            xpi = row[0];
            xpf = row[LSTM_D];
            xpg = row[2 * LSTM_D];
            xpo = row[3 * LSTM_D];
        }

        // Wave 0 polls the 32 per-wg flags; bounded spin converts deadlock
        // into fast-wrong-finish (diagnosable).
        if (t > 0 && wave == 0) {
            const unsigned target = (unsigned)t;
            int spins = 0;
            for (;;) {
                unsigned f = (lane < REC_G)
                    ? __hip_atomic_load(&flags[lane], __ATOMIC_ACQUIRE,
                                        __HIP_MEMORY_SCOPE_AGENT)
                    : target;
                if (__ballot(f >= target) == ~0ull) break;
                if (++spins > (1 << 14)) break;
            }
        }
        __syncthreads();

        // Stage h (512 f) into LDS: threads 0..127, 4 agent-scope scalar
        // loads each (coalesced per wave), bypassing stale L1.
        const float* hsrc = (t == 0) ? h0 : (hbuf + ((t - 1) & 1) * LSTM_D);
        if (tid < 128) {
            const float* s = hsrc + tid * 4;
            float4 hv;
            hv.x = __hip_atomic_load(s + 0, __ATOMIC_RELAXED, __HIP_MEMORY_SCOPE_AGENT);
            hv.y = __hip_atomic_load(s + 1, __ATOMIC_RELAXED, __HIP_MEMORY_SCOPE_AGENT);
            hv.z = __hip_atomic_load(s + 2, __ATOMIC_RELAXED, __HIP_MEMORY_SCOPE_AGENT);
            hv.w = __hip_atomic_load(s + 3, __ATOMIC_RELAXED, __HIP_MEMORY_SCOPE_AGENT);
            *(float4*)(hs + tid * 4) = hv;
        }
        __syncthreads();

        float a0 = 0.f, a1 = 0.f, a2 = 0.f, a3 = 0.f;
#pragma unroll
        for (int j = 0; j < 8; ++j) {
            // Rotated chunk: part p reads chunk (j+p)&7 of its k-range ->
            // across the wave each bank serves <=2 addresses (free).
            float4 h4 = *(const float4*)(hs + p * 32 + (((j + p) & 7) << 2));
            a0 = fmaf(h4.x, w[4*j+0].x, a0);
            a1 = fmaf(h4.x, w[4*j+0].y, a1);
            a2 = fmaf(h4.x, w[4*j+0].z, a2);
            a3 = fmaf(h4.x, w[4*j+0].w, a3);
            a0 = fmaf(h4.y, w[4*j+1].x, a0);
            a1 = fmaf(h4.y, w[4*j+1].y, a1);
            a2 = fmaf(h4.y, w[4*j+1].z, a2);
            a3 = fmaf(h4.y, w[4*j+1].w, a3);
            a0 = fmaf(h4.z, w[4*j+2].x, a0);
            a1 = fmaf(h4.z, w[4*j+2].y, a1);
            a2 = fmaf(h4.z, w[4*j+2].z, a2);
            a3 = fmaf(h4.z, w[4*j+2].w, a3);
            a0 = fmaf(h4.w, w[4*j+3].x, a0);
            a1 = fmaf(h4.w, w[4*j+3].y, a1);
            a2 = fmaf(h4.w, w[4*j+3].z, a2);
            a3 = fmaf(h4.w, w[4*j+3].w, a3);
        }

        // Reduce across the 16 k-parts (lane bits 2..5).
#pragma unroll
        for (int m = 4; m <= 32; m <<= 1) {
            a0 += __shfl_xor(a0, m, 64);
            a1 += __shfl_xor(a1, m, 64);
            a2 += __shfl_xor(a2, m, 64);
            a3 += __shfl_xor(a3, m, 64);
        }

        if (head) {
            float yi = xpi + a0;
            float yf = xpf + a1;
            float yg = xpg + a2;
            float yo = xpo + a3;
            float si = 1.f / (1.f + __expf(-yi));
            float sf = 1.f / (1.f + __expf(-yf));
            float so = 1.f / (1.f + __expf(-yo));
            float tg = tanhf(yg);
            c_val = fmaf(sf, c_val, si * tg);
            float h = so * tanhf(c_val);
            out[(size_t)t * LSTM_D + d_glob] = h;
            __hip_atomic_store(hbuf + (t & 1) * LSTM_D + d_glob, h,
                               __ATOMIC_RELAXED, __HIP_MEMORY_SCOPE_AGENT);
        }

        // Barrier drains each wave's vmcnt -> all h stores are at the
        // coherence point before tid 0 publishes the flag.
        __syncthreads();
        if (tid == 0)
            __hip_atomic_store(&flags[g], (unsigned)(t + 1), __ATOMIC_RELEASE,
                               __HIP_MEMORY_SCOPE_AGENT);
    }

    if (head) cbuf[d_glob] = c_val;   // c carry for next chunk launch
}

// ---------------------------------------------------------------------------
extern "C" void kernel_launch(void* const* d_in, const int* in_sizes, int n_in,
                              void* d_out, int out_size, void* d_ws, size_t ws_size,
                              hipStream_t stream)
{
    const float* xs = (const float*)d_in[0];   // [L, 512]
    const float* Wi = (const float*)d_in[1];   // [512, 2048]
    const float* Wh = (const float*)d_in[2];   // [512, 2048]
    const float* b  = (const float*)d_in[3];   // [2048]
    const float* c0 = (const float*)d_in[4];   // [512]
    const float* h0 = (const float*)d_in[5];   // [512]
    float* out = (float*)d_out;                // [L, 512]

    uint8_t* ws = (uint8_t*)d_ws;
    unsigned int* flags = (unsigned int*)ws;
    float*  hbuf  = (float*)(ws + 256);
    float*  cbuf  = (float*)(ws + 4608);
    float4* wpack = (float4*)(ws + WS_WPACK_OFF);
    float*  xbuf  = (float*)(ws + WS_XBUF_OFF);

    // Largest power-of-two chunk whose xbuf fits in the workspace.
    int C = LSTM_L;
    while (C > 64 &&
           WS_XBUF_OFF + (size_t)C * LSTM_4D * sizeof(float) > ws_size)
        C >>= 1;

    (void)hipMemsetAsync(ws, 0, 8192, stream);   // flags/hbuf/cbuf zeroed

    pack_wh<<<REC_G, 256, 0, stream>>>(Wh, wpack);

    const int nChunks = LSTM_L / C;
    for (int k = 0; k < nChunks; ++k) {
        dim3 ggrid(LSTM_4D / 64, C / 64);
        gemm_xproj<<<ggrid, 256, 0, stream>>>(xs + (size_t)k * C * LSTM_D,
                                              Wi, b, xbuf);
        lstm_rec<<<REC_G, 256, 0, stream>>>(wpack, xbuf, h0, c0, out,
                                            flags, hbuf, cbuf, k * C, C);
    }
}

// Round 5
// 116107.690 us; speedup vs baseline: 1.2790x; 1.2091x over previous
//
#include <hip/hip_runtime.h>
#include <cstdint>
#include <cstddef>

#define LSTM_D  512
#define LSTM_4D 2048
#define LSTM_L  32768
#define REC_G   32      // workgroups in recurrent kernel
#define REC_DPW 16      // d-indices per workgroup
#define REC_THR (REC_G * 256)   // 8192 recurrent threads

// Workspace layout:
//   ws +     0 : flags[32] (u32)  per-wg step-completion flags
//   ws +   256 : hbuf (2*512 f)   double-buffered h
//   ws +  4608 : cbuf (512 f)     c carry between chunk launches
//   ws + 65536 : wpack (8192*32 float4 = 4 MB) packed Wh
//   ws + 65536 + 4 MB : xbuf (C*2048 f) x-projection chunk
#define WS_WPACK_OFF 65536
#define WS_XBUF_OFF  (65536 + (size_t)REC_THR * 32 * sizeof(float4))

// ---------------------------------------------------------------------------
// GEMM: xbuf[C][2048] = xs_chunk[C][512] @ Wi[512][2048] + b
// ---------------------------------------------------------------------------
__global__ __launch_bounds__(256)
void gemm_xproj(const float* __restrict__ A,
                const float* __restrict__ B,
                const float* __restrict__ bias,
                float* __restrict__ C)
{
    __shared__ float As[16][64];   // [k][row]
    __shared__ float Bs[16][64];   // [k][col]
    const int tid  = threadIdx.x;
    const int row0 = blockIdx.y * 64;
    const int col0 = blockIdx.x * 64;
    const int tx   = tid & 15;
    const int ty   = tid >> 4;
    const int lr   = tid >> 2;
    const int lk4  = (tid & 3) * 4;
    const int bk   = tid >> 4;
    const int bc4  = (tid & 15) * 4;

    float acc[4][4] = {};

    for (int k0 = 0; k0 < LSTM_D; k0 += 16) {
        float4 av = *(const float4*)(A + (size_t)(row0 + lr) * LSTM_D + k0 + lk4);
        float4 bv = *(const float4*)(B + (size_t)(k0 + bk) * LSTM_4D + col0 + bc4);
        __syncthreads();
        As[lk4 + 0][lr] = av.x;
        As[lk4 + 1][lr] = av.y;
        As[lk4 + 2][lr] = av.z;
        As[lk4 + 3][lr] = av.w;
        *(float4*)(&Bs[bk][bc4]) = bv;
        __syncthreads();
#pragma unroll
        for (int k = 0; k < 16; ++k) {
            float4 a4 = *(const float4*)(&As[k][ty * 4]);
            float4 b4 = *(const float4*)(&Bs[k][tx * 4]);
            acc[0][0] = fmaf(a4.x, b4.x, acc[0][0]);
            acc[0][1] = fmaf(a4.x, b4.y, acc[0][1]);
            acc[0][2] = fmaf(a4.x, b4.z, acc[0][2]);
            acc[0][3] = fmaf(a4.x, b4.w, acc[0][3]);
            acc[1][0] = fmaf(a4.y, b4.x, acc[1][0]);
            acc[1][1] = fmaf(a4.y, b4.y, acc[1][1]);
            acc[1][2] = fmaf(a4.y, b4.z, acc[1][2]);
            acc[1][3] = fmaf(a4.y, b4.w, acc[1][3]);
            acc[2][0] = fmaf(a4.z, b4.x, acc[2][0]);
            acc[2][1] = fmaf(a4.z, b4.y, acc[2][1]);
            acc[2][2] = fmaf(a4.z, b4.z, acc[2][2]);
            acc[2][3] = fmaf(a4.z, b4.w, acc[2][3]);
            acc[3][0] = fmaf(a4.w, b4.x, acc[3][0]);
            acc[3][1] = fmaf(a4.w, b4.y, acc[3][1]);
            acc[3][2] = fmaf(a4.w, b4.z, acc[3][2]);
            acc[3][3] = fmaf(a4.w, b4.w, acc[3][3]);
        }
    }

    float4 bb = *(const float4*)(bias + col0 + tx * 4);
#pragma unroll
    for (int i = 0; i < 4; ++i) {
        float4 o;
        o.x = acc[i][0] + bb.x;
        o.y = acc[i][1] + bb.y;
        o.z = acc[i][2] + bb.z;
        o.w = acc[i][3] + bb.w;
        *(float4*)(C + (size_t)(row0 + ty * 4 + i) * LSTM_4D + col0 + tx * 4) = o;
    }
}

// ---------------------------------------------------------------------------
// Pack Wh into per-thread register-load order (see lstm_rec layout comment).
// ---------------------------------------------------------------------------
__global__ __launch_bounds__(256)
void pack_wh(const float* __restrict__ Wh, float4* __restrict__ wp)
{
    const int thr  = blockIdx.x * 256 + threadIdx.x;
    const int g    = thr >> 8;
    const int tid  = thr & 255;
    const int wave = tid >> 6;
    const int lane = tid & 63;
    const int p    = lane >> 2;
    const int d_in = lane & 3;
    const int d    = g * REC_DPW + wave * 4 + d_in;

    for (int j = 0; j < 8; ++j) {
        const int c = (j + p) & 7;
        for (int e = 0; e < 4; ++e) {
            const int k = p * 32 + c * 4 + e;
            float4 w;
            w.x = Wh[(size_t)k * LSTM_4D + 0 * LSTM_D + d];
            w.y = Wh[(size_t)k * LSTM_4D + 1 * LSTM_D + d];
            w.z = Wh[(size_t)k * LSTM_4D + 2 * LSTM_D + d];
            w.w = Wh[(size_t)k * LSTM_4D + 3 * LSTM_D + d];
            wp[(size_t)(j * 4 + e) * REC_THR + thr] = w;
        }
    }
}

// ---------------------------------------------------------------------------
// Persistent recurrent kernel, one chunk of `steps` steps from t0.
// Weights held in 128 VGPRs per thread, PINNED via opaque empty asm so the
// compiler cannot sink/rematerialize the loads into the t-loop (that reload
// was the round-3/4 bottleneck: VGPR_Count 88 << 128 proved non-residency).
// Sync: per-wg flags + ballot poll; h double-buffered in global, staged
// through LDS. Buffer-reuse safety: entering step t+2 requires all flags
// >= t+2, i.e. every wg finished step t+1 whose reads of buffer (t&1)
// precede its flag publication.
// ---------------------------------------------------------------------------
__global__ __launch_bounds__(256, 1)
void lstm_rec(const float4* __restrict__ wp,
              const float* __restrict__ xp,    // chunk's [steps][2048]
              const float* __restrict__ h0,
              const float* __restrict__ c0,
              float* __restrict__ out,
              unsigned int* __restrict__ flags,
              float* __restrict__ hbuf,        // 2 * 512 floats
              float* __restrict__ cbuf,        // 512 floats
              int t0, int steps)
{
    __shared__ float hs[LSTM_D];

    const int g      = blockIdx.x;
    const int tid    = threadIdx.x;
    const int wave   = tid >> 6;
    const int lane   = tid & 63;
    const int p      = lane >> 2;               // k-part 0..15
    const int d_in   = lane & 3;
    const int d_glob = g * REC_DPW + wave * 4 + d_in;
    const bool head  = (p == 0);
    const int  thr   = g * 256 + tid;

    // Weights: 32 float4 = 128 VGPRs, all indices compile-time constant.
    float4 w[32];
#pragma unroll
    for (int i = 0; i < 32; ++i)
        w[i] = wp[(size_t)i * REC_THR + thr];
    // Pin every component in a VGPR: empty asm is opaque & unmovable, so the
    // values cannot be rematerialized by re-loading inside the t-loop.
#pragma unroll
    for (int i = 0; i < 32; ++i)
        asm volatile("" : "+v"(w[i].x), "+v"(w[i].y), "+v"(w[i].z), "+v"(w[i].w));

    float c_val = 0.f;
    if (head) c_val = (t0 == 0) ? c0[d_glob] : cbuf[d_glob];

    for (int ts = 0; ts < steps; ++ts) {
        const int t = t0 + ts;

        // Prefetch x_proj row (independent of h) before any waiting.
        float xpi = 0.f, xpf = 0.f, xpg = 0.f, xpo = 0.f;
        if (head) {
            const float* row = xp + (size_t)ts * LSTM_4D + d_glob;
            xpi = row[0];
            xpf = row[LSTM_D];
            xpg = row[2 * LSTM_D];
            xpo = row[3 * LSTM_D];
        }

        // Wave 0 polls the 32 per-wg flags; bounded spin converts deadlock
        // into fast-wrong-finish (diagnosable).
        if (t > 0 && wave == 0) {
            const unsigned target = (unsigned)t;
            int spins = 0;
            for (;;) {
                unsigned f = (lane < REC_G)
                    ? __hip_atomic_load(&flags[lane], __ATOMIC_ACQUIRE,
                                        __HIP_MEMORY_SCOPE_AGENT)
                    : target;
                if (__ballot(f >= target) == ~0ull) break;
                if (++spins > (1 << 14)) break;
            }
        }
        __syncthreads();

        // Stage h (512 f) into LDS: threads 0..127, 4 agent-scope loads
        // each (coalesced per wave), bypassing stale L1.
        const float* hsrc = (t == 0) ? h0 : (hbuf + ((t - 1) & 1) * LSTM_D);
        if (tid < 128) {
            const float* s = hsrc + tid * 4;
            float4 hv;
            hv.x = __hip_atomic_load(s + 0, __ATOMIC_RELAXED, __HIP_MEMORY_SCOPE_AGENT);
            hv.y = __hip_atomic_load(s + 1, __ATOMIC_RELAXED, __HIP_MEMORY_SCOPE_AGENT);
            hv.z = __hip_atomic_load(s + 2, __ATOMIC_RELAXED, __HIP_MEMORY_SCOPE_AGENT);
            hv.w = __hip_atomic_load(s + 3, __ATOMIC_RELAXED, __HIP_MEMORY_SCOPE_AGENT);
            *(float4*)(hs + tid * 4) = hv;
        }
        __syncthreads();

        float a0 = 0.f, a1 = 0.f, a2 = 0.f, a3 = 0.f;
#pragma unroll
        for (int j = 0; j < 8; ++j) {
            // Rotated chunk: part p reads chunk (j+p)&7 of its k-range ->
            // across the wave each bank serves <=2 addresses (free).
            float4 h4 = *(const float4*)(hs + p * 32 + (((j + p) & 7) << 2));
            a0 = fmaf(h4.x, w[4*j+0].x, a0);
            a1 = fmaf(h4.x, w[4*j+0].y, a1);
            a2 = fmaf(h4.x, w[4*j+0].z, a2);
            a3 = fmaf(h4.x, w[4*j+0].w, a3);
            a0 = fmaf(h4.y, w[4*j+1].x, a0);
            a1 = fmaf(h4.y, w[4*j+1].y, a1);
            a2 = fmaf(h4.y, w[4*j+1].z, a2);
            a3 = fmaf(h4.y, w[4*j+1].w, a3);
            a0 = fmaf(h4.z, w[4*j+2].x, a0);
            a1 = fmaf(h4.z, w[4*j+2].y, a1);
            a2 = fmaf(h4.z, w[4*j+2].z, a2);
            a3 = fmaf(h4.z, w[4*j+2].w, a3);
            a0 = fmaf(h4.w, w[4*j+3].x, a0);
            a1 = fmaf(h4.w, w[4*j+3].y, a1);
            a2 = fmaf(h4.w, w[4*j+3].z, a2);
            a3 = fmaf(h4.w, w[4*j+3].w, a3);
        }

        // Reduce across the 16 k-parts (lane bits 2..5).
#pragma unroll
        for (int m = 4; m <= 32; m <<= 1) {
            a0 += __shfl_xor(a0, m, 64);
            a1 += __shfl_xor(a1, m, 64);
            a2 += __shfl_xor(a2, m, 64);
            a3 += __shfl_xor(a3, m, 64);
        }

        if (head) {
            float yi = xpi + a0;
            float yf = xpf + a1;
            float yg = xpg + a2;
            float yo = xpo + a3;
            float si = 1.f / (1.f + __expf(-yi));
            float sf = 1.f / (1.f + __expf(-yf));
            float so = 1.f / (1.f + __expf(-yo));
            float tg = tanhf(yg);
            c_val = fmaf(sf, c_val, si * tg);
            float h = so * tanhf(c_val);
            out[(size_t)t * LSTM_D + d_glob] = h;
            __hip_atomic_store(hbuf + (t & 1) * LSTM_D + d_glob, h,
                               __ATOMIC_RELAXED, __HIP_MEMORY_SCOPE_AGENT);
        }

        // Barrier drains each wave's vmcnt -> all h stores are at the
        // coherence point before tid 0 publishes the flag.
        __syncthreads();
        if (tid == 0)
            __hip_atomic_store(&flags[g], (unsigned)(t + 1), __ATOMIC_RELEASE,
                               __HIP_MEMORY_SCOPE_AGENT);
    }

    if (head) cbuf[d_glob] = c_val;   // c carry for next chunk launch
}

// ---------------------------------------------------------------------------
extern "C" void kernel_launch(void* const* d_in, const int* in_sizes, int n_in,
                              void* d_out, int out_size, void* d_ws, size_t ws_size,
                              hipStream_t stream)
{
    const float* xs = (const float*)d_in[0];   // [L, 512]
    const float* Wi = (const float*)d_in[1];   // [512, 2048]
    const float* Wh = (const float*)d_in[2];   // [512, 2048]
    const float* b  = (const float*)d_in[3];   // [2048]
    const float* c0 = (const float*)d_in[4];   // [512]
    const float* h0 = (const float*)d_in[5];   // [512]
    float* out = (float*)d_out;                // [L, 512]

    uint8_t* ws = (uint8_t*)d_ws;
    unsigned int* flags = (unsigned int*)ws;
    float*  hbuf  = (float*)(ws + 256);
    float*  cbuf  = (float*)(ws + 4608);
    float4* wpack = (float4*)(ws + WS_WPACK_OFF);
    float*  xbuf  = (float*)(ws + WS_XBUF_OFF);

    // Largest power-of-two chunk whose xbuf fits in the workspace.
    int C = LSTM_L;
    while (C > 64 &&
           WS_XBUF_OFF + (size_t)C * LSTM_4D * sizeof(float) > ws_size)
        C >>= 1;

    (void)hipMemsetAsync(ws, 0, 8192, stream);   // flags/hbuf/cbuf zeroed

    pack_wh<<<REC_G, 256, 0, stream>>>(Wh, wpack);

    const int nChunks = LSTM_L / C;
    for (int k = 0; k < nChunks; ++k) {
        dim3 ggrid(LSTM_4D / 64, C / 64);
        gemm_xproj<<<ggrid, 256, 0, stream>>>(xs + (size_t)k * C * LSTM_D,
                                              Wi, b, xbuf);
        lstm_rec<<<REC_G, 256, 0, stream>>>(wpack, xbuf, h0, c0, out,
                                            flags, hbuf, cbuf, k * C, C);
    }
}

// Round 7
// 97306.665 us; speedup vs baseline: 1.5261x; 1.1932x over previous
//
#include <hip/hip_runtime.h>
#include <cstdint>
#include <cstddef>

#define LSTM_D  512
#define LSTM_4D 2048
#define LSTM_L  32768
#define REC_G   64               // workgroups; each owns 8 d-indices
#define REC_DPW 8

typedef float f32x4 __attribute__((ext_vector_type(4)));  // native v4f32 for asm "v"

// Workspace layout:
//   ws +    0 : hbuf pairs, 2 buffers x 256 f32x4 = 8 KB
//               pair j of buffer B at ws + B*4096 + j*16:
//               {h[2j], h[2j+1], tag, 0}
//   ws + 8192 : cbuf (512 f) c carry between chunk launches
//   ws + 65536: wpack (64 wg * 4096 float4 = 4 MB) swizzled Wh
//   ws + 65536 + 4 MB : xbuf (C*2048 f) x-projection chunk
#define WS_CBUF_OFF  8192
#define WS_WPACK_OFF 65536
#define WS_XBUF_OFF  (65536 + (size_t)REC_G * 4096 * sizeof(float4))

// ---------------------------------------------------------------------------
// GEMM: xbuf[C][2048] = xs_chunk[C][512] @ Wi[512][2048] + b
// ---------------------------------------------------------------------------
__global__ __launch_bounds__(256)
void gemm_xproj(const float* __restrict__ A,
                const float* __restrict__ B,
                const float* __restrict__ bias,
                float* __restrict__ C)
{
    __shared__ float As[16][64];
    __shared__ float Bs[16][64];
    const int tid  = threadIdx.x;
    const int row0 = blockIdx.y * 64;
    const int col0 = blockIdx.x * 64;
    const int tx   = tid & 15;
    const int ty   = tid >> 4;
    const int lr   = tid >> 2;
    const int lk4  = (tid & 3) * 4;
    const int bk   = tid >> 4;
    const int bc4  = (tid & 15) * 4;

    float acc[4][4] = {};

    for (int k0 = 0; k0 < LSTM_D; k0 += 16) {
        float4 av = *(const float4*)(A + (size_t)(row0 + lr) * LSTM_D + k0 + lk4);
        float4 bv = *(const float4*)(B + (size_t)(k0 + bk) * LSTM_4D + col0 + bc4);
        __syncthreads();
        As[lk4 + 0][lr] = av.x;
        As[lk4 + 1][lr] = av.y;
        As[lk4 + 2][lr] = av.z;
        As[lk4 + 3][lr] = av.w;
        *(float4*)(&Bs[bk][bc4]) = bv;
        __syncthreads();
#pragma unroll
        for (int k = 0; k < 16; ++k) {
            float4 a4 = *(const float4*)(&As[k][ty * 4]);
            float4 b4 = *(const float4*)(&Bs[k][tx * 4]);
            acc[0][0] = fmaf(a4.x, b4.x, acc[0][0]);
            acc[0][1] = fmaf(a4.x, b4.y, acc[0][1]);
            acc[0][2] = fmaf(a4.x, b4.z, acc[0][2]);
            acc[0][3] = fmaf(a4.x, b4.w, acc[0][3]);
            acc[1][0] = fmaf(a4.y, b4.x, acc[1][0]);
            acc[1][1] = fmaf(a4.y, b4.y, acc[1][1]);
            acc[1][2] = fmaf(a4.y, b4.z, acc[1][2]);
            acc[1][3] = fmaf(a4.y, b4.w, acc[1][3]);
            acc[2][0] = fmaf(a4.z, b4.x, acc[2][0]);
            acc[2][1] = fmaf(a4.z, b4.y, acc[2][1]);
            acc[2][2] = fmaf(a4.z, b4.z, acc[2][2]);
            acc[2][3] = fmaf(a4.z, b4.w, acc[2][3]);
            acc[3][0] = fmaf(a4.w, b4.x, acc[3][0]);
            acc[3][1] = fmaf(a4.w, b4.y, acc[3][1]);
            acc[3][2] = fmaf(a4.w, b4.z, acc[3][2]);
            acc[3][3] = fmaf(a4.w, b4.w, acc[3][3]);
        }
    }

    float4 bb = *(const float4*)(bias + col0 + tx * 4);
#pragma unroll
    for (int i = 0; i < 4; ++i) {
        float4 o;
        o.x = acc[i][0] + bb.x;
        o.y = acc[i][1] + bb.y;
        o.z = acc[i][2] + bb.z;
        o.w = acc[i][3] + bb.w;
        *(float4*)(C + (size_t)(row0 + ty * 4 + i) * LSTM_4D + col0 + tx * 4) = o;
    }
}

// ---------------------------------------------------------------------------
// Swizzled Wh pack. LDS view per wg: float4 W[4096]; group index
// gidx = wave*1024 + lane*16 + mphys. Logical m = mphys ^ (lane&15),
// g = m>>2 (gate), gi = m&3 (k quad), p = lane>>1 (k-part), d_in = lane&1,
// d = wg*8 + wave*2 + d_in, k = p*16 + gi*4 + e.
// XOR swizzle -> each wave64 ds_read_b128 spreads uniformly across banks.
// ---------------------------------------------------------------------------
__global__ __launch_bounds__(256)
void pack_wh(const float* __restrict__ Wh, float4* __restrict__ wp)
{
    const int wg  = blockIdx.x;
    const int tid = threadIdx.x;
    for (int s = 0; s < 16; ++s) {
        const int gidx  = s * 256 + tid;
        const int wave  = gidx >> 10;
        const int lane  = (gidx >> 4) & 63;
        const int mphys = gidx & 15;
        const int m     = mphys ^ (lane & 15);
        const int g     = m >> 2;
        const int gi    = m & 3;
        const int p     = lane >> 1;
        const int d     = wg * REC_DPW + wave * 2 + (lane & 1);
        const int k     = p * 16 + gi * 4;
        float4 v;
        v.x = Wh[(size_t)(k + 0) * LSTM_4D + g * LSTM_D + d];
        v.y = Wh[(size_t)(k + 1) * LSTM_4D + g * LSTM_D + d];
        v.z = Wh[(size_t)(k + 2) * LSTM_4D + g * LSTM_D + d];
        v.w = Wh[(size_t)(k + 3) * LSTM_4D + g * LSTM_D + d];
        wp[(size_t)wg * 4096 + gidx] = v;
    }
}

// ---------------------------------------------------------------------------
// Init tagged h buffers: buf1 pairs = {h0[2j], h0[2j+1], -1, 0} (consumed by
// step 0, which reads buffer (0-1)&1 = 1 expecting tag -1); buf0 tag = -2.
// ---------------------------------------------------------------------------
__global__ void init_h(const float* __restrict__ h0, f32x4* __restrict__ hb)
{
    const int j = threadIdx.x;            // 0..255
    f32x4 a; a.x = h0[2 * j]; a.y = h0[2 * j + 1]; a.z = -1.0f; a.w = 0.0f;
    f32x4 z; z.x = 0.0f;      z.y = 0.0f;          z.z = -2.0f; z.w = 0.0f;
    hb[256 + j] = a;
    hb[j]       = z;
}

// ---------------------------------------------------------------------------
// Coherent 16B ops straight to/from the coherence point (sc0 sc1 = bypass
// L1/L2 caching): tag travels in the same 16B flit as the data -> no
// fences, no separate flags.
// ---------------------------------------------------------------------------
__device__ inline void load8_cohere(const f32x4* p, f32x4 h[8])
{
    asm volatile(
        "global_load_dwordx4 %0, %8, off sc0 sc1\n\t"
        "global_load_dwordx4 %1, %8, off offset:16 sc0 sc1\n\t"
        "global_load_dwordx4 %2, %8, off offset:32 sc0 sc1\n\t"
        "global_load_dwordx4 %3, %8, off offset:48 sc0 sc1\n\t"
        "global_load_dwordx4 %4, %8, off offset:64 sc0 sc1\n\t"
        "global_load_dwordx4 %5, %8, off offset:80 sc0 sc1\n\t"
        "global_load_dwordx4 %6, %8, off offset:96 sc0 sc1\n\t"
        "global_load_dwordx4 %7, %8, off offset:112 sc0 sc1\n\t"
        "s_waitcnt vmcnt(0)"
        : "=&v"(h[0]), "=&v"(h[1]), "=&v"(h[2]), "=&v"(h[3]),
          "=&v"(h[4]), "=&v"(h[5]), "=&v"(h[6]), "=&v"(h[7])
        : "v"(p)
        : "memory");
}

__device__ inline void store_cohere(f32x4* p, f32x4 v)
{
    asm volatile("global_store_dwordx4 %0, %1, off sc0 sc1"
                 :: "v"(p), "v"(v) : "memory");
}

// ---------------------------------------------------------------------------
// Barrier-free persistent recurrent kernel. 64 wgs x 256 thr (64 KB LDS
// each, 1 wg/CU). Wave owns 2 adjacent d's; lane: p = lane>>1 (k-part of
// 16 h's), d_in = lane&1. Weights live in LDS (loaded once). Per step each
// wave: spin on 8 tagged 16B loads until all tags == t-1, FMA from LDS
// weights, 5x shfl_xor reduce over p, gates on lanes 0/1, publish one
// tagged 16B pair-store. No __syncthreads in the step loop.
// Buffer reuse safe: a wave publishes t only after consuming t-1, so
// observing all t-tags implies all t-1 reads retired before (t+1)&1 is
// overwritten.
// ---------------------------------------------------------------------------
__global__ __launch_bounds__(256, 1)
void lstm_rec(const float4* __restrict__ wp,
              const float* __restrict__ xp,    // chunk's [steps][2048]
              const float* __restrict__ c0,
              float* __restrict__ out,
              f32x4* __restrict__ hb,          // 2 x 256 tagged pairs
              float* __restrict__ cbuf,        // 512 floats
              int t0, int steps)
{
    __shared__ float4 W[4096];                 // exactly 64 KB

    const int wg   = blockIdx.x;
    const int tid  = threadIdx.x;
    const int wave = tid >> 6;
    const int lane = tid & 63;
    const int p    = lane >> 1;
    const int d    = wg * REC_DPW + wave * 2 + (lane & 1);
    const int d0   = wg * REC_DPW + wave * 2;  // wave's first d
    const int mybase = wave * 1024 + lane * 16;
    const int lx   = lane & 15;

    // One-time LDS weight fill (coalesced 64 KB copy), the only barrier.
#pragma unroll
    for (int s = 0; s < 16; ++s)
        W[s * 256 + tid] = wp[(size_t)wg * 4096 + s * 256 + tid];
    __syncthreads();

    float c_val = 0.f;
    if (lane < 2) c_val = (t0 == 0) ? c0[d] : cbuf[d];

    int dead = 0;

    for (int ts = 0; ts < steps; ++ts) {
        const int t = t0 + ts;

        // xp prefetch (independent of h), lanes 0/1 only.
        float xpi = 0.f, xpf = 0.f, xpg = 0.f, xpo = 0.f;
        if (lane < 2) {
            const float* row = xp + (size_t)ts * LSTM_4D + d;
            xpi = row[0];
            xpf = row[LSTM_D];
            xpg = row[2 * LSTM_D];
            xpo = row[3 * LSTM_D];
        }

        // Tagged spin-consume: pairs p*8 .. p*8+7 of buffer (t-1)&1.
        const float  exp_tag = (float)(t - 1);
        const f32x4* src = hb + ((t + 1) & 1) * 256 + p * 8;
        f32x4 hp[8];
        int tries = 0;
        for (;;) {
            load8_cohere(src, hp);
            bool ok = (hp[0].z == exp_tag) & (hp[1].z == exp_tag) &
                      (hp[2].z == exp_tag) & (hp[3].z == exp_tag) &
                      (hp[4].z == exp_tag) & (hp[5].z == exp_tag) &
                      (hp[6].z == exp_tag) & (hp[7].z == exp_tag);
            if (dead || (__ballot(ok) == ~0ull)) break;
            if (++tries > (1 << 16)) { dead = 1; break; }
        }

        float h[16];
#pragma unroll
        for (int j = 0; j < 8; ++j) {
            h[2 * j]     = hp[j].x;
            h[2 * j + 1] = hp[j].y;
        }

        // FMA from LDS weights (xor-swizzled, bank-uniform).
        float a0 = 0.f, a1 = 0.f, a2 = 0.f, a3 = 0.f;
#pragma unroll
        for (int gi = 0; gi < 4; ++gi) {
            float4 w0 = W[mybase + ((0 * 4 + gi) ^ lx)];
            float4 w1 = W[mybase + ((1 * 4 + gi) ^ lx)];
            float4 w2 = W[mybase + ((2 * 4 + gi) ^ lx)];
            float4 w3 = W[mybase + ((3 * 4 + gi) ^ lx)];
            const float h0v = h[gi * 4 + 0], h1v = h[gi * 4 + 1];
            const float h2v = h[gi * 4 + 2], h3v = h[gi * 4 + 3];
            a0 = fmaf(h0v, w0.x, a0); a0 = fmaf(h1v, w0.y, a0);
            a0 = fmaf(h2v, w0.z, a0); a0 = fmaf(h3v, w0.w, a0);
            a1 = fmaf(h0v, w1.x, a1); a1 = fmaf(h1v, w1.y, a1);
            a1 = fmaf(h2v, w1.z, a1); a1 = fmaf(h3v, w1.w, a1);
            a2 = fmaf(h0v, w2.x, a2); a2 = fmaf(h1v, w2.y, a2);
            a2 = fmaf(h2v, w2.z, a2); a2 = fmaf(h3v, w2.w, a2);
            a3 = fmaf(h0v, w3.x, a3); a3 = fmaf(h1v, w3.y, a3);
            a3 = fmaf(h2v, w3.z, a3); a3 = fmaf(h3v, w3.w, a3);
        }

        // Reduce over p (lane bits 1..5).
#pragma unroll
        for (int m = 2; m <= 32; m <<= 1) {
            a0 += __shfl_xor(a0, m, 64);
            a1 += __shfl_xor(a1, m, 64);
            a2 += __shfl_xor(a2, m, 64);
            a3 += __shfl_xor(a3, m, 64);
        }

        float hval = 0.f;
        if (lane < 2) {
            float yi = xpi + a0;
            float yf = xpf + a1;
            float yg = xpg + a2;
            float yo = xpo + a3;
            float si = 1.f / (1.f + __expf(-yi));
            float sf = 1.f / (1.f + __expf(-yf));
            float so = 1.f / (1.f + __expf(-yo));
            float tg = tanhf(yg);
            c_val = fmaf(sf, c_val, si * tg);
            hval  = so * tanhf(c_val);
        }
        const float h_nb = __shfl(hval, 1);   // lane 1's h (d0+1)

        if (lane == 0) {
            *(float2*)(out + (size_t)t * LSTM_D + d0) = make_float2(hval, h_nb);
            f32x4 pub; pub.x = hval; pub.y = h_nb; pub.z = (float)t; pub.w = 0.f;
            store_cohere(hb + (t & 1) * 256 + (wg * 4 + wave), pub);
        }
    }

    if (lane < 2) cbuf[d] = c_val;   // c carry for next chunk launch
}

// ---------------------------------------------------------------------------
extern "C" void kernel_launch(void* const* d_in, const int* in_sizes, int n_in,
                              void* d_out, int out_size, void* d_ws, size_t ws_size,
                              hipStream_t stream)
{
    const float* xs = (const float*)d_in[0];   // [L, 512]
    const float* Wi = (const float*)d_in[1];   // [512, 2048]
    const float* Wh = (const float*)d_in[2];   // [512, 2048]
    const float* b  = (const float*)d_in[3];   // [2048]
    const float* c0 = (const float*)d_in[4];   // [512]
    const float* h0 = (const float*)d_in[5];   // [512]
    float* out = (float*)d_out;                // [L, 512]

    uint8_t* ws = (uint8_t*)d_ws;
    f32x4*  hb    = (f32x4*)ws;
    float*  cbuf  = (float*)(ws + WS_CBUF_OFF);
    float4* wpack = (float4*)(ws + WS_WPACK_OFF);
    float*  xbuf  = (float*)(ws + WS_XBUF_OFF);

    // Largest power-of-two chunk whose xbuf fits in the workspace.
    int C = LSTM_L;
    while (C > 64 &&
           WS_XBUF_OFF + (size_t)C * LSTM_4D * sizeof(float) > ws_size)
        C >>= 1;

    init_h<<<1, 256, 0, stream>>>(h0, hb);
    pack_wh<<<REC_G, 256, 0, stream>>>(Wh, wpack);

    const int nChunks = LSTM_L / C;
    for (int k = 0; k < nChunks; ++k) {
        dim3 ggrid(LSTM_4D / 64, C / 64);
        gemm_xproj<<<ggrid, 256, 0, stream>>>(xs + (size_t)k * C * LSTM_D,
                                              Wi, b, xbuf);
        lstm_rec<<<REC_G, 256, 0, stream>>>(wpack, xbuf, c0, out,
                                            hb, cbuf, k * C, C);
    }
}

// Round 8
// 76275.220 us; speedup vs baseline: 1.9469x; 1.2757x over previous
//
#include <hip/hip_runtime.h>
#include <cstdint>
#include <cstddef>

#define LSTM_D  512
#define LSTM_4D 2048
#define LSTM_L  32768
#define REC_G   64               // workgroups; each owns 8 d-indices
#define REC_DPW 8
#define N_REPL  8                // h-buffer replicas (channel spreading)

typedef float f32x4 __attribute__((ext_vector_type(4)));  // native v4f32 for asm "v"

// Workspace layout:
//   ws +      0 : hb, 8 replicas x (2 buffers x 256 f32x4) = 64 KB
//                 replica r, buffer B, flit j at hb[r*512 + B*256 + j]
//                 flit = {h[2j], h[2j+1], tag, 0}
//   ws +  65536 : cbuf (512 f) c carry between chunk launches
//   ws + 131072 : wpack (64 wg * 4096 float4 = 4 MB) swizzled Wh
//   ws + 131072 + 4 MB : xbuf (C*2048 f) x-projection chunk
#define WS_CBUF_OFF  65536
#define WS_WPACK_OFF 131072
#define WS_XBUF_OFF  (131072 + (size_t)REC_G * 4096 * sizeof(float4))

// ---------------------------------------------------------------------------
// GEMM: xbuf[C][2048] = xs_chunk[C][512] @ Wi[512][2048] + b
// ---------------------------------------------------------------------------
__global__ __launch_bounds__(256)
void gemm_xproj(const float* __restrict__ A,
                const float* __restrict__ B,
                const float* __restrict__ bias,
                float* __restrict__ C)
{
    __shared__ float As[16][64];
    __shared__ float Bs[16][64];
    const int tid  = threadIdx.x;
    const int row0 = blockIdx.y * 64;
    const int col0 = blockIdx.x * 64;
    const int tx   = tid & 15;
    const int ty   = tid >> 4;
    const int lr   = tid >> 2;
    const int lk4  = (tid & 3) * 4;
    const int bk   = tid >> 4;
    const int bc4  = (tid & 15) * 4;

    float acc[4][4] = {};

    for (int k0 = 0; k0 < LSTM_D; k0 += 16) {
        float4 av = *(const float4*)(A + (size_t)(row0 + lr) * LSTM_D + k0 + lk4);
        float4 bv = *(const float4*)(B + (size_t)(k0 + bk) * LSTM_4D + col0 + bc4);
        __syncthreads();
        As[lk4 + 0][lr] = av.x;
        As[lk4 + 1][lr] = av.y;
        As[lk4 + 2][lr] = av.z;
        As[lk4 + 3][lr] = av.w;
        *(float4*)(&Bs[bk][bc4]) = bv;
        __syncthreads();
#pragma unroll
        for (int k = 0; k < 16; ++k) {
            float4 a4 = *(const float4*)(&As[k][ty * 4]);
            float4 b4 = *(const float4*)(&Bs[k][tx * 4]);
            acc[0][0] = fmaf(a4.x, b4.x, acc[0][0]);
            acc[0][1] = fmaf(a4.x, b4.y, acc[0][1]);
            acc[0][2] = fmaf(a4.x, b4.z, acc[0][2]);
            acc[0][3] = fmaf(a4.x, b4.w, acc[0][3]);
            acc[1][0] = fmaf(a4.y, b4.x, acc[1][0]);
            acc[1][1] = fmaf(a4.y, b4.y, acc[1][1]);
            acc[1][2] = fmaf(a4.y, b4.z, acc[1][2]);
            acc[1][3] = fmaf(a4.y, b4.w, acc[1][3]);
            acc[2][0] = fmaf(a4.z, b4.x, acc[2][0]);
            acc[2][1] = fmaf(a4.z, b4.y, acc[2][1]);
            acc[2][2] = fmaf(a4.z, b4.z, acc[2][2]);
            acc[2][3] = fmaf(a4.z, b4.w, acc[2][3]);
            acc[3][0] = fmaf(a4.w, b4.x, acc[3][0]);
            acc[3][1] = fmaf(a4.w, b4.y, acc[3][1]);
            acc[3][2] = fmaf(a4.w, b4.z, acc[3][2]);
            acc[3][3] = fmaf(a4.w, b4.w, acc[3][3]);
        }
    }

    float4 bb = *(const float4*)(bias + col0 + tx * 4);
#pragma unroll
    for (int i = 0; i < 4; ++i) {
        float4 o;
        o.x = acc[i][0] + bb.x;
        o.y = acc[i][1] + bb.y;
        o.z = acc[i][2] + bb.z;
        o.w = acc[i][3] + bb.w;
        *(float4*)(C + (size_t)(row0 + ty * 4 + i) * LSTM_4D + col0 + tx * 4) = o;
    }
}

// ---------------------------------------------------------------------------
// Swizzled Wh pack (unchanged from round 7; see lstm_rec layout comment).
// ---------------------------------------------------------------------------
__global__ __launch_bounds__(256)
void pack_wh(const float* __restrict__ Wh, float4* __restrict__ wp)
{
    const int wg  = blockIdx.x;
    const int tid = threadIdx.x;
    for (int s = 0; s < 16; ++s) {
        const int gidx  = s * 256 + tid;
        const int wave  = gidx >> 10;
        const int lane  = (gidx >> 4) & 63;
        const int mphys = gidx & 15;
        const int m     = mphys ^ (lane & 15);
        const int g     = m >> 2;
        const int gi    = m & 3;
        const int p     = lane >> 1;
        const int d     = wg * REC_DPW + wave * 2 + (lane & 1);
        const int k     = p * 16 + gi * 4;
        float4 v;
        v.x = Wh[(size_t)(k + 0) * LSTM_4D + g * LSTM_D + d];
        v.y = Wh[(size_t)(k + 1) * LSTM_4D + g * LSTM_D + d];
        v.z = Wh[(size_t)(k + 2) * LSTM_4D + g * LSTM_D + d];
        v.w = Wh[(size_t)(k + 3) * LSTM_4D + g * LSTM_D + d];
        wp[(size_t)wg * 4096 + gidx] = v;
    }
}

// ---------------------------------------------------------------------------
// Init tagged h replicas: block r inits replica r. Buffer 1 = h0 with tag -1
// (step 0 reads buffer (0-1)&1 = 1 expecting tag -1); buffer 0 tag = -2.
// ---------------------------------------------------------------------------
__global__ void init_h(const float* __restrict__ h0, f32x4* __restrict__ hb)
{
    const int r = blockIdx.x;             // replica 0..7
    const int j = threadIdx.x;            // 0..255
    f32x4 a; a.x = h0[2 * j]; a.y = h0[2 * j + 1]; a.z = -1.0f; a.w = 0.0f;
    f32x4 z; z.x = 0.0f;      z.y = 0.0f;          z.z = -2.0f; z.w = 0.0f;
    hb[r * 512 + 256 + j] = a;
    hb[r * 512 + j]       = z;
}

// ---------------------------------------------------------------------------
// Coherent 16B ops straight to/from the coherence point (sc0 sc1 bypass
// L1/L2): tag travels in the same 16B flit as the data.
// ---------------------------------------------------------------------------
__device__ inline void load8_cohere(const f32x4* p, f32x4 h[8])
{
    asm volatile(
        "global_load_dwordx4 %0, %8, off sc0 sc1\n\t"
        "global_load_dwordx4 %1, %8, off offset:16 sc0 sc1\n\t"
        "global_load_dwordx4 %2, %8, off offset:32 sc0 sc1\n\t"
        "global_load_dwordx4 %3, %8, off offset:48 sc0 sc1\n\t"
        "global_load_dwordx4 %4, %8, off offset:64 sc0 sc1\n\t"
        "global_load_dwordx4 %5, %8, off offset:80 sc0 sc1\n\t"
        "global_load_dwordx4 %6, %8, off offset:96 sc0 sc1\n\t"
        "global_load_dwordx4 %7, %8, off offset:112 sc0 sc1\n\t"
        "s_waitcnt vmcnt(0)"
        : "=&v"(h[0]), "=&v"(h[1]), "=&v"(h[2]), "=&v"(h[3]),
          "=&v"(h[4]), "=&v"(h[5]), "=&v"(h[6]), "=&v"(h[7])
        : "v"(p)
        : "memory");
}

__device__ inline void store_cohere(f32x4* p, f32x4 v)
{
    asm volatile("global_store_dwordx4 %0, %1, off sc0 sc1"
                 :: "v"(p), "v"(v) : "memory");
}

// ---------------------------------------------------------------------------
// Barrier-free persistent recurrent kernel (round-7 structure) + 8x h-buffer
// replication: publishers (lanes 0/1, 4 stores each) write all replicas;
// consumer wave reads only replica wg&7 -> spin hot-spot contention /8.
// Buffer reuse safety unchanged: a wave publishes t only after consuming
// t-1, so all-t-tags visible implies all t-1 reads retired.
// ---------------------------------------------------------------------------
__global__ __launch_bounds__(256, 1)
void lstm_rec(const float4* __restrict__ wp,
              const float* __restrict__ xp,    // chunk's [steps][2048]
              const float* __restrict__ c0,
              float* __restrict__ out,
              f32x4* __restrict__ hb,          // 8 x 2 x 256 tagged pairs
              float* __restrict__ cbuf,        // 512 floats
              int t0, int steps)
{
    __shared__ float4 W[4096];                 // exactly 64 KB

    const int wg   = blockIdx.x;
    const int tid  = threadIdx.x;
    const int wave = tid >> 6;
    const int lane = tid & 63;
    const int p    = lane >> 1;
    const int d    = wg * REC_DPW + wave * 2 + (lane & 1);
    const int d0   = wg * REC_DPW + wave * 2;  // wave's first d
    const int mybase = wave * 1024 + lane * 16;
    const int lx   = lane & 15;
    const int fj   = wg * 4 + wave;            // this wave's flit index
    const int myrep = wg & 7;                  // consumer replica

    // One-time LDS weight fill (coalesced 64 KB copy), the only barrier.
#pragma unroll
    for (int s = 0; s < 16; ++s)
        W[s * 256 + tid] = wp[(size_t)wg * 4096 + s * 256 + tid];
    __syncthreads();

    float c_val = 0.f;
    if (lane < 2) c_val = (t0 == 0) ? c0[d] : cbuf[d];

    int dead = 0;

    for (int ts = 0; ts < steps; ++ts) {
        const int t = t0 + ts;

        // xp prefetch (independent of h), lanes 0/1 only.
        float xpi = 0.f, xpf = 0.f, xpg = 0.f, xpo = 0.f;
        if (lane < 2) {
            const float* row = xp + (size_t)ts * LSTM_4D + d;
            xpi = row[0];
            xpf = row[LSTM_D];
            xpg = row[2 * LSTM_D];
            xpo = row[3 * LSTM_D];
        }

        // Tagged spin-consume from replica wg&7: pairs p*8..p*8+7 of buffer
        // (t-1)&1.
        const float  exp_tag = (float)(t - 1);
        const f32x4* src = hb + myrep * 512 + ((t + 1) & 1) * 256 + p * 8;
        f32x4 hp[8];
        int tries = 0;
        for (;;) {
            load8_cohere(src, hp);
            bool ok = (hp[0].z == exp_tag) & (hp[1].z == exp_tag) &
                      (hp[2].z == exp_tag) & (hp[3].z == exp_tag) &
                      (hp[4].z == exp_tag) & (hp[5].z == exp_tag) &
                      (hp[6].z == exp_tag) & (hp[7].z == exp_tag);
            if (dead || (__ballot(ok) == ~0ull)) break;
            if (++tries > (1 << 16)) { dead = 1; break; }
        }

        float h[16];
#pragma unroll
        for (int j = 0; j < 8; ++j) {
            h[2 * j]     = hp[j].x;
            h[2 * j + 1] = hp[j].y;
        }

        // FMA from LDS weights (xor-swizzled, bank-uniform).
        float a0 = 0.f, a1 = 0.f, a2 = 0.f, a3 = 0.f;
#pragma unroll
        for (int gi = 0; gi < 4; ++gi) {
            float4 w0 = W[mybase + ((0 * 4 + gi) ^ lx)];
            float4 w1 = W[mybase + ((1 * 4 + gi) ^ lx)];
            float4 w2 = W[mybase + ((2 * 4 + gi) ^ lx)];
            float4 w3 = W[mybase + ((3 * 4 + gi) ^ lx)];
            const float h0v = h[gi * 4 + 0], h1v = h[gi * 4 + 1];
            const float h2v = h[gi * 4 + 2], h3v = h[gi * 4 + 3];
            a0 = fmaf(h0v, w0.x, a0); a0 = fmaf(h1v, w0.y, a0);
            a0 = fmaf(h2v, w0.z, a0); a0 = fmaf(h3v, w0.w, a0);
            a1 = fmaf(h0v, w1.x, a1); a1 = fmaf(h1v, w1.y, a1);
            a1 = fmaf(h2v, w1.z, a1); a1 = fmaf(h3v, w1.w, a1);
            a2 = fmaf(h0v, w2.x, a2); a2 = fmaf(h1v, w2.y, a2);
            a2 = fmaf(h2v, w2.z, a2); a2 = fmaf(h3v, w2.w, a2);
            a3 = fmaf(h0v, w3.x, a3); a3 = fmaf(h1v, w3.y, a3);
            a3 = fmaf(h2v, w3.z, a3); a3 = fmaf(h3v, w3.w, a3);
        }

        // Reduce over p (lane bits 1..5).
#pragma unroll
        for (int m = 2; m <= 32; m <<= 1) {
            a0 += __shfl_xor(a0, m, 64);
            a1 += __shfl_xor(a1, m, 64);
            a2 += __shfl_xor(a2, m, 64);
            a3 += __shfl_xor(a3, m, 64);
        }

        float hval = 0.f;
        if (lane < 2) {
            float yi = xpi + a0;
            float yf = xpf + a1;
            float yg = xpg + a2;
            float yo = xpo + a3;
            float si = 1.f / (1.f + __expf(-yi));
            float sf = 1.f / (1.f + __expf(-yf));
            float so = 1.f / (1.f + __expf(-yo));
            float tg = tanhf(yg);
            c_val = fmaf(sf, c_val, si * tg);
            hval  = so * tanhf(c_val);
        }
        const float h_other = __shfl_xor(hval, 1, 64);  // partner d's h

        // Publish FIRST (critical path), out store after. Lanes 0/1 each
        // write 4 replicas.
        if (lane < 2) {
            f32x4 pub;
            pub.x = (lane == 0) ? hval : h_other;
            pub.y = (lane == 0) ? h_other : hval;
            pub.z = (float)t;
            pub.w = 0.0f;
            f32x4* dst = hb + (size_t)(lane * 4) * 512 + (t & 1) * 256 + fj;
            store_cohere(dst + 0 * 512, pub);
            store_cohere(dst + 1 * 512, pub);
            store_cohere(dst + 2 * 512, pub);
            store_cohere(dst + 3 * 512, pub);
        }

        if (lane == 0)
            *(float2*)(out + (size_t)t * LSTM_D + d0) = make_float2(hval, h_other);
    }

    if (lane < 2) cbuf[d] = c_val;   // c carry for next chunk launch
}

// ---------------------------------------------------------------------------
extern "C" void kernel_launch(void* const* d_in, const int* in_sizes, int n_in,
                              void* d_out, int out_size, void* d_ws, size_t ws_size,
                              hipStream_t stream)
{
    const float* xs = (const float*)d_in[0];   // [L, 512]
    const float* Wi = (const float*)d_in[1];   // [512, 2048]
    const float* Wh = (const float*)d_in[2];   // [512, 2048]
    const float* b  = (const float*)d_in[3];   // [2048]
    const float* c0 = (const float*)d_in[4];   // [512]
    const float* h0 = (const float*)d_in[5];   // [512]
    float* out = (float*)d_out;                // [L, 512]

    uint8_t* ws = (uint8_t*)d_ws;
    f32x4*  hb    = (f32x4*)ws;
    float*  cbuf  = (float*)(ws + WS_CBUF_OFF);
    float4* wpack = (float4*)(ws + WS_WPACK_OFF);
    float*  xbuf  = (float*)(ws + WS_XBUF_OFF);

    // Largest power-of-two chunk whose xbuf fits in the workspace.
    int C = LSTM_L;
    while (C > 64 &&
           WS_XBUF_OFF + (size_t)C * LSTM_4D * sizeof(float) > ws_size)
        C >>= 1;

    init_h<<<N_REPL, 256, 0, stream>>>(h0, hb);
    pack_wh<<<REC_G, 256, 0, stream>>>(Wh, wpack);

    const int nChunks = LSTM_L / C;
    for (int k = 0; k < nChunks; ++k) {
        dim3 ggrid(LSTM_4D / 64, C / 64);
        gemm_xproj<<<ggrid, 256, 0, stream>>>(xs + (size_t)k * C * LSTM_D,
                                              Wi, b, xbuf);
        lstm_rec<<<REC_G, 256, 0, stream>>>(wpack, xbuf, c0, out,
                                            hb, cbuf, k * C, C);
    }
}